// Round 1
// baseline (157.448 us; speedup 1.0000x reference)
//
#include <hip/hip_runtime.h>

#define B_ROWS 2048
#define S_LEN 8192
#define PER_LANE 32
#define TILE_ELEMS (64 * PER_LANE)   // 2048
#define NTILES (S_LEN / TILE_ELEMS)  // 4
#define WPB 4                        // waves (rows) per block
#define NBLOCKS (B_ROWS / WPB)       // 512

// ---- compile-time decay constants ----
constexpr double cpowi(double b, int e) { double r = 1.0; for (int i = 0; i < e; ++i) r *= b; return r; }
// avoid denormal/underflow weirdness in double->float constexpr conversion
constexpr float tof(double x) { return (x < 1.2e-38 && x > -1.2e-38) ? 0.0f : (float)x; }

#define A0f 0.1f
#define A1f 0.3f
#define A2f 0.6f

constexpr float D0_1 = tof(cpowi(0.9, 32)),  D0_2 = tof(cpowi(0.9, 64)),  D0_4 = tof(cpowi(0.9, 128));
constexpr float D0_8 = tof(cpowi(0.9, 256)), D0_16 = tof(cpowi(0.9, 512)), D0_32 = tof(cpowi(0.9, 1024));
constexpr float D1_1 = tof(cpowi(0.7, 32)),  D1_2 = tof(cpowi(0.7, 64)),  D1_4 = tof(cpowi(0.7, 128));
constexpr float D1_8 = tof(cpowi(0.7, 256)), D1_16 = tof(cpowi(0.7, 512)), D1_32 = tof(cpowi(0.7, 1024));
constexpr float D2_1 = tof(cpowi(0.4, 32)),  D2_2 = tof(cpowi(0.4, 64)),  D2_4 = tof(cpowi(0.4, 128));
constexpr float D2_8 = tof(cpowi(0.4, 256)), D2_16 = tof(cpowi(0.4, 512)), D2_32 = tof(cpowi(0.4, 1024));

// Kogge-Stone inclusive scan for linear recurrence with uniform per-lane decay D:
// v_l = sum_{j<=l} D^(l-j) L_j    (d_k = D^(2^k))
__device__ __forceinline__ float ema_scan(float v, int lane,
                                          float d1, float d2, float d4,
                                          float d8, float d16, float d32) {
    float u;
    u = __shfl_up(v, 1);  v += (lane >= 1  ? d1  : 0.0f) * u;
    u = __shfl_up(v, 2);  v += (lane >= 2  ? d2  : 0.0f) * u;
    u = __shfl_up(v, 4);  v += (lane >= 4  ? d4  : 0.0f) * u;
    u = __shfl_up(v, 8);  v += (lane >= 8  ? d8  : 0.0f) * u;
    u = __shfl_up(v, 16); v += (lane >= 16 ? d16 : 0.0f) * u;
    u = __shfl_up(v, 32); v += (lane >= 32 ? d32 : 0.0f) * u;
    return v;
}

__device__ __forceinline__ float huber(float pd, float td) {
    float dir = pd * td;
    float se  = fabsf(pd - td);
    float mm  = fmaxf(1.0f - dir, 0.0f);
    float q   = 0.5f * mm * mm;
    return dir < 0.0f ? se : q;
}

__global__ void __launch_bounds__(256) msl_main(const float* __restrict__ pred,
                                                const float* __restrict__ targ,
                                                float* __restrict__ partial) {
    const int lane = threadIdx.x & 63;
    const int wave = threadIdx.x >> 6;
    const int row  = blockIdx.x * WPB + wave;
    const float* __restrict__ prow = pred + (size_t)row * S_LEN;
    const float* __restrict__ trow = targ + (size_t)row * S_LEN;

    // EMA state at the end of the previous tile (valid from tile 1 on)
    float sp0 = 0.f, sp1 = 0.f, sp2 = 0.f, st0 = 0.f, st1 = 0.f, st2 = 0.f;
    float acc0 = 0.f, acc1 = 0.f, acc2 = 0.f;

    for (int tile = 0; tile < NTILES; ++tile) {
        const int base = tile * TILE_ELEMS + lane * PER_LANE;
        float xp[PER_LANE], xt[PER_LANE];
        const float4* p4 = reinterpret_cast<const float4*>(prow + base);
        const float4* t4 = reinterpret_cast<const float4*>(trow + base);
#pragma unroll
        for (int j = 0; j < PER_LANE / 4; ++j) {
            float4 a = p4[j];
            float4 b = t4[j];
            xp[4 * j + 0] = a.x; xp[4 * j + 1] = a.y; xp[4 * j + 2] = a.z; xp[4 * j + 3] = a.w;
            xt[4 * j + 0] = b.x; xt[4 * j + 1] = b.y; xt[4 * j + 2] = b.z; xt[4 * j + 3] = b.w;
        }

        const bool first = (tile == 0);
        const bool lz    = (lane == 0);

        // ---- pass 1: lane-local EMA (carry-in: tile state for lane 0, else 0) ----
        // tile0/lane0: init to x[0]; the j=0 update x0 + a*(x0-x0) keeps it exactly x0,
        // matching the reference's pe[0] = x[0] initial condition.
        float Lp0 = lz ? (first ? xp[0] : sp0) : 0.0f;
        float Lp1 = lz ? (first ? xp[0] : sp1) : 0.0f;
        float Lp2 = lz ? (first ? xp[0] : sp2) : 0.0f;
        float Lt0 = lz ? (first ? xt[0] : st0) : 0.0f;
        float Lt1 = lz ? (first ? xt[0] : st1) : 0.0f;
        float Lt2 = lz ? (first ? xt[0] : st2) : 0.0f;
#pragma unroll
        for (int j = 0; j < PER_LANE; ++j) {
            Lp0 += A0f * (xp[j] - Lp0);
            Lp1 += A1f * (xp[j] - Lp1);
            Lp2 += A2f * (xp[j] - Lp2);
            Lt0 += A0f * (xt[j] - Lt0);
            Lt1 += A1f * (xt[j] - Lt1);
            Lt2 += A2f * (xt[j] - Lt2);
        }

        // ---- wave scan: exact EMA value at the end of each lane's chunk ----
        float vp0 = ema_scan(Lp0, lane, D0_1, D0_2, D0_4, D0_8, D0_16, D0_32);
        float vp1 = ema_scan(Lp1, lane, D1_1, D1_2, D1_4, D1_8, D1_16, D1_32);
        float vp2 = ema_scan(Lp2, lane, D2_1, D2_2, D2_4, D2_8, D2_16, D2_32);
        float vt0 = ema_scan(Lt0, lane, D0_1, D0_2, D0_4, D0_8, D0_16, D0_32);
        float vt1 = ema_scan(Lt1, lane, D1_1, D1_2, D1_4, D1_8, D1_16, D1_32);
        float vt2 = ema_scan(Lt2, lane, D2_1, D2_2, D2_4, D2_8, D2_16, D2_32);

        // exclusive carry (EMA value just before this lane's chunk)
        float cp0 = __shfl_up(vp0, 1), cp1 = __shfl_up(vp1, 1), cp2 = __shfl_up(vp2, 1);
        float ct0 = __shfl_up(vt0, 1), ct1 = __shfl_up(vt1, 1), ct2 = __shfl_up(vt2, 1);

        float yp0 = lz ? (first ? xp[0] : sp0) : cp0;
        float yp1 = lz ? (first ? xp[0] : sp1) : cp1;
        float yp2 = lz ? (first ? xp[0] : sp2) : cp2;
        float yt0 = lz ? (first ? xt[0] : st0) : ct0;
        float yt1 = lz ? (first ? xt[0] : st1) : ct1;
        float yt2 = lz ? (first ? xt[0] : st2) : ct2;

        // tile-exit state -> carry into next tile's lane 0
        sp0 = __shfl(vp0, 63); sp1 = __shfl(vp1, 63); sp2 = __shfl(vp2, 63);
        st0 = __shfl(vt0, 63); st1 = __shfl(vt1, 63); st2 = __shfl(vt2, 63);

        // ---- pass 2: replay with exact carry, accumulate huber on the deltas ----
        // pd_t = pe_t - pe_{t-1} = a*(x_t - pe_{t-1})
        const float skip = (first && lz) ? 0.0f : 1.0f;  // no loss term for t=0
#pragma unroll
        for (int j = 0; j < PER_LANE; ++j) {
            float pd0 = A0f * (xp[j] - yp0); yp0 += pd0;
            float td0 = A0f * (xt[j] - yt0); yt0 += td0;
            float pd1 = A1f * (xp[j] - yp1); yp1 += pd1;
            float td1 = A1f * (xt[j] - yt1); yt1 += td1;
            float pd2 = A2f * (xp[j] - yp2); yp2 += pd2;
            float td2 = A2f * (xt[j] - yt2); yt2 += td2;

            float h0 = huber(pd0, td0);
            float h1 = huber(pd1, td1);
            float h2 = huber(pd2, td2);
            if (j == 0) { h0 *= skip; h1 *= skip; h2 *= skip; }
            acc0 += h0; acc1 += h1; acc2 += h2;
        }
    }

    // weight the three scales, reduce across the wave (row), then across the block
    float wacc = 0.5f * acc0 + 0.3f * acc1 + 0.2f * acc2;
#pragma unroll
    for (int o = 32; o > 0; o >>= 1) wacc += __shfl_down(wacc, o);

    __shared__ float sred[WPB];
    if (lane == 0) sred[wave] = wacc;
    __syncthreads();
    if (threadIdx.x == 0)
        partial[blockIdx.x] = sred[0] + sred[1] + sred[2] + sred[3];
}

__global__ void __launch_bounds__(256) msl_reduce(const float* __restrict__ partial,
                                                  float* __restrict__ out) {
    const int tid = threadIdx.x;
    float v = partial[tid] + partial[tid + 256];
#pragma unroll
    for (int o = 32; o > 0; o >>= 1) v += __shfl_down(v, o);
    __shared__ float s[4];
    if ((tid & 63) == 0) s[tid >> 6] = v;
    __syncthreads();
    if (tid == 0)
        out[0] = (s[0] + s[1] + s[2] + s[3]) *
                 (float)(1.0 / ((double)(S_LEN - 1) * (double)B_ROWS));
}

extern "C" void kernel_launch(void* const* d_in, const int* in_sizes, int n_in,
                              void* d_out, int out_size, void* d_ws, size_t ws_size,
                              hipStream_t stream) {
    const float* pred = (const float*)d_in[0];
    const float* targ = (const float*)d_in[1];
    float* out = (float*)d_out;
    float* partial = (float*)d_ws;  // 512 floats = 2 KB

    msl_main<<<NBLOCKS, 256, 0, stream>>>(pred, targ, partial);
    msl_reduce<<<1, 256, 0, stream>>>(partial, out);
}